// Round 5
// baseline (332.624 us; speedup 1.0000x reference)
//
#include <hip/hip_runtime.h>
#include <math.h>

constexpr int kN = 20000;
constexpr int kD = 8;
constexpr int kE = 100000;
constexpr int kM = kN * 9;            // 180000 level-1 rows
constexpr int kTiles1 = kM / 16;      // 11250
constexpr int kTiles3 = kN / 16;      // 1250
constexpr int kGroups = kN / 16;      // 1250 groups of 16 nodes = 144 rows
constexpr float kEps = 1e-5f;

// stats float indices
constexpr int S_SUM1 = 0, S_SQ1 = 128, S_SUM2 = 256, S_SQ2 = 320;

// ws layout (bytes). agg1 frag-layout bf16 [kM][64] = 23.04 MB, then agg2,
// pre2, embs, embsW, stats. Peak ~43.5 MB (< proven 61.5 MB).
constexpr size_t OFF_AGG2  = 23040000;   // bf16 [kN][128] = 5.12 MB
constexpr size_t OFF_PRE2  = 28160000;   // f32 [kN][64]
constexpr size_t OFF_EMBS  = 33280000;
constexpr size_t OFF_EMBSW = 38400000;
constexpr size_t OFF_STATS = 43520000;   // 384 floats

typedef short short8 __attribute__((ext_vector_type(8)));
typedef float floatx4 __attribute__((ext_vector_type(4)));

__device__ __forceinline__ unsigned f2bf(float f) {  // f32 -> bf16 (RNE)
  unsigned u = __float_as_uint(f);
  u += 0x7fffu + ((u >> 16) & 1u);
  return u >> 16;
}

// ---------------------------------------------------------------------------
// K1a: one wave per level-1 row m. lane = feature. Masked-mean gather of 9
// x-rows; store agg1 bf16 in MFMA A-FRAGMENT order:
//   addr(m,k) = (m/16)*1024 + (k/8)*128 + (m%16)*8 + (k%8)   [shorts]
// Block 0 also zeros the stats block (consumed first by k1s, next kernel).
// ---------------------------------------------------------------------------
__global__ __launch_bounds__(256) void k1a_gather(
    const float* __restrict__ x, const float* __restrict__ node_ts,
    const int* __restrict__ nidx, const float* __restrict__ nts,
    unsigned short* __restrict__ agg1, float* __restrict__ stats)
{
  if (blockIdx.x == 0 && threadIdx.x < 384) stats[threadIdx.x] = 0.f;
  const int m = blockIdx.x * 4 + (threadIdx.x >> 6);
  const int lane = threadIdx.x & 63;
  const int n = (int)((unsigned)m / 9u);
  const int slot = m - n * 9;
  int c; float t;
  if (slot < kD) { c = nidx[n * kD + slot]; t = nts[n * kD + slot]; }
  else           { c = n;                   t = node_ts[n]; }
  c = __builtin_amdgcn_readfirstlane(c);
  float s = x[c * 64 + lane];
  float fcnt = 1.f;
#pragma unroll
  for (int j = 0; j < kD; ++j) {
    int cj = nidx[c * kD + j];
    float w = (nts[c * kD + j] <= t) ? 1.f : 0.f;
    s = fmaf(w, x[cj * 64 + lane], s);
    fcnt += w;
  }
  float v = s / fcnt;
  const int tt = m >> 4, r = m & 15, g = lane >> 3, jj = lane & 7;
  agg1[tt * 1024 + g * 128 + r * 8 + jj] = (unsigned short)f2bf(v);
}

// ---------------------------------------------------------------------------
// K1s: stats-only GEMM1 pass. MFMA over all tiles, accumulate column
// sum/sumsq of (acc + b1); NO pre1 store. Block LDS reduce, atomic per col.
// ---------------------------------------------------------------------------
__global__ __launch_bounds__(256, 3) void k1s_stats(
    const unsigned short* __restrict__ aggA,
    const float* __restrict__ W1, const float* __restrict__ b1,
    float* __restrict__ stats)
{
  __shared__ unsigned short W1T[128 * 72];
  __shared__ float redS[256][8];
  __shared__ float redQ[256][8];

  const int tid = threadIdx.x;
  const int lane = tid & 63;
  const int wave = tid >> 6;
  const int l15 = lane & 15;
  const int q = lane >> 4;

  for (int i = tid; i < 8192; i += 256) {
    int n = i >> 6, k = i & 63;
    W1T[n * 72 + k] = (unsigned short)f2bf(W1[k * 128 + n]);
  }
  __syncthreads();

  short8 bf[8][2];
#pragma unroll
  for (int c = 0; c < 8; ++c)
#pragma unroll
    for (int s = 0; s < 2; ++s)
      bf[c][s] = *(const short8*)&W1T[(c * 16 + l15) * 72 + q * 8 + s * 32];

  float b1c[8];
#pragma unroll
  for (int c = 0; c < 8; ++c) b1c[c] = b1[c * 16 + l15];

  float sum8[8], sq8[8];
#pragma unroll
  for (int c = 0; c < 8; ++c) { sum8[c] = 0.f; sq8[c] = 0.f; }

  const int gw = blockIdx.x * 4 + wave;
  const int nw = gridDim.x * 4;

  for (int t = gw; t < kTiles1; t += nw) {
    const unsigned short* ap = aggA + (size_t)t * 1024;
    short8 af0 = *(const short8*)(ap + q * 128 + l15 * 8);
    short8 af1 = *(const short8*)(ap + (4 + q) * 128 + l15 * 8);

    floatx4 acc[8];
#pragma unroll
    for (int c = 0; c < 8; ++c) {
      acc[c] = (floatx4){0.f, 0.f, 0.f, 0.f};
      acc[c] = __builtin_amdgcn_mfma_f32_16x16x32_bf16(af0, bf[c][0], acc[c], 0, 0, 0);
      acc[c] = __builtin_amdgcn_mfma_f32_16x16x32_bf16(af1, bf[c][1], acc[c], 0, 0, 0);
    }
#pragma unroll
    for (int c = 0; c < 8; ++c)
#pragma unroll
      for (int i = 0; i < 4; ++i) {
        float v = acc[c][i] + b1c[c];
        sum8[c] += v; sq8[c] += v * v;
      }
  }

  __syncthreads();
#pragma unroll
  for (int c = 0; c < 8; ++c) { redS[tid][c] = sum8[c]; redQ[tid][c] = sq8[c]; }
  __syncthreads();
  if (tid < 128) {
    int c = tid >> 4, r15 = tid & 15;
    float s = 0.f, qq = 0.f;
#pragma unroll
    for (int w = 0; w < 4; ++w)
#pragma unroll
      for (int p = 0; p < 4; ++p) {
        int T = w * 64 + p * 16 + r15;
        s += redS[T][c]; qq += redQ[T][c];
      }
    atomicAdd(&stats[S_SUM1 + tid], s);
    atomicAdd(&stats[S_SQ1 + tid], qq);
  }
}

// ---------------------------------------------------------------------------
// K2: apply pass. One block per 16-node group (144 rows = 9 MFMA tiles,
// exact). GEMM1 recompute -> BN1+ReLU in C-frags (BN finalized block-locally
// from raw stats) -> weighted accumulate into LDS agg[16][128] via LDS
// atomics -> masked-mean divide -> agg2 bf16 [kN][128]. pre1 never
// touches HBM.
// ---------------------------------------------------------------------------
__global__ __launch_bounds__(256, 3) void k2_apply(
    const unsigned short* __restrict__ aggA, const float* __restrict__ node_ts,
    const float* __restrict__ nts, const float* __restrict__ W1,
    const float* __restrict__ b1, const float* __restrict__ g1,
    const float* __restrict__ be1, const float* __restrict__ stats,
    unsigned* __restrict__ agg2dw)
{
  __shared__ unsigned short W1T[128 * 72];
  __shared__ float sc[128], sh[128];
  __shared__ float wbuf[144];
  __shared__ float rvs[16];
  __shared__ float aggl[16 * 128];   // 8 KB f32 accumulators

  const int tid = threadIdx.x;
  const int lane = tid & 63;
  const int wave = tid >> 6;
  const int l15 = lane & 15;
  const int q = lane >> 4;
  const int g = blockIdx.x;          // group id, exact kGroups
  const int n0 = g * 16;

  for (int i = tid; i < 8192; i += 256) {
    int n = i >> 6, k = i & 63;
    W1T[n * 72 + k] = (unsigned short)f2bf(W1[k * 128 + n]);
  }
  if (tid < 128) {
    float mean = stats[S_SUM1 + tid] * (1.f / kM);
    float var  = stats[S_SQ1 + tid] * (1.f / kM) - mean * mean;
    float s    = g1[tid] * rsqrtf(var + kEps);
    sc[tid] = s; sh[tid] = be1[tid] - mean * s;
  }
  if (tid < 144) {
    int nd = n0 + tid / 9, slot = tid % 9;
    wbuf[tid] = (slot < kD) ? ((nts[nd * kD + slot] <= node_ts[nd]) ? 1.f : 0.f)
                            : 1.f;
  }
  __syncthreads();

  short8 bfr[8][2];
#pragma unroll
  for (int c = 0; c < 8; ++c)
#pragma unroll
    for (int s = 0; s < 2; ++s)
      bfr[c][s] = *(const short8*)&W1T[(c * 16 + l15) * 72 + q * 8 + s * 32];

  float scc[8], shc[8];
#pragma unroll
  for (int c = 0; c < 8; ++c) {
    int col = c * 16 + l15;
    scc[c] = sc[col];
    shc[c] = fmaf(b1[col], sc[col], sh[col]);   // fold bias into BN shift
  }
  if (tid < 16) {
    float s = 0.f;
#pragma unroll
    for (int j = 0; j < 9; ++j) s += wbuf[tid * 9 + j];
    rvs[tid] = 1.f / s;
  }
#pragma unroll
  for (int p = 0; p < 8; ++p) aggl[tid + 256 * p] = 0.f;  // 2048 f32
  __syncthreads();

  for (int t9 = wave; t9 < 9; t9 += 4) {
    const unsigned short* ap = aggA + (size_t)(g * 9 + t9) * 1024;
    short8 af0 = *(const short8*)(ap + q * 128 + l15 * 8);
    short8 af1 = *(const short8*)(ap + (4 + q) * 128 + l15 * 8);

    floatx4 acc[8];
#pragma unroll
    for (int c = 0; c < 8; ++c) {
      acc[c] = (floatx4){0.f, 0.f, 0.f, 0.f};
      acc[c] = __builtin_amdgcn_mfma_f32_16x16x32_bf16(af0, bfr[c][0], acc[c], 0, 0, 0);
      acc[c] = __builtin_amdgcn_mfma_f32_16x16x32_bf16(af1, bfr[c][1], acc[c], 0, 0, 0);
    }
#pragma unroll
    for (int i = 0; i < 4; ++i) {
      int r = t9 * 16 + q * 4 + i;          // local row in [0,144)
      int ndl = (int)((unsigned)r / 9u);    // local node
      float w = wbuf[r];
#pragma unroll
      for (int c = 0; c < 8; ++c) {
        int col = c * 16 + l15;
        float h = fmaxf(fmaf(acc[c][i], scc[c], shc[c]), 0.f);
        atomicAdd(&aggl[ndl * 128 + col], w * h);
      }
    }
  }
  __syncthreads();

  // write agg2: 16 nodes x 64 bf16x2 dwords = 1024 dwords (4 x 256 threads),
  // coalesced. (R4 bug: looped p<8 -> OOB aggl/rvs reads + cross-group
  // agg2 corruption. 1024 dwords needs exactly p<4.)
#pragma unroll
  for (int p = 0; p < 4; ++p) {
    int idx = tid + 256 * p;               // 0..1023
    int ndl = idx >> 6, cp = idx & 63;
    float r = rvs[ndl];
    float v0 = aggl[ndl * 128 + 2 * cp] * r;
    float v1 = aggl[ndl * 128 + 2 * cp + 1] * r;
    agg2dw[(size_t)(n0 + ndl) * 64 + cp] = f2bf(v0) | (f2bf(v1) << 16);
  }
}

// ---------------------------------------------------------------------------
// K3b: MFMA GEMM2: agg2 [N][128] x W2 [128][64] + b2 -> pre2 f32, BN2 stats.
// ---------------------------------------------------------------------------
__global__ __launch_bounds__(256, 3) void k3b_gemm2(
    const unsigned short* __restrict__ agg2, const float* __restrict__ W2,
    const float* __restrict__ b2, float* __restrict__ stats,
    float* __restrict__ pre2)
{
  __shared__ unsigned short W2T[64 * 136];
  __shared__ float redS[256][4];
  __shared__ float redQ[256][4];

  const int tid = threadIdx.x;
  const int lane = tid & 63;
  const int wave = tid >> 6;
  const int l15 = lane & 15;
  const int q = lane >> 4;

  for (int i = tid; i < 8192; i += 256) {
    int n = i >> 7, k = i & 127;
    W2T[n * 136 + k] = (unsigned short)f2bf(W2[k * 64 + n]);
  }
  __syncthreads();

  short8 bfr[4][4];
#pragma unroll
  for (int c = 0; c < 4; ++c)
#pragma unroll
    for (int s = 0; s < 4; ++s)
      bfr[c][s] = *(const short8*)&W2T[(c * 16 + l15) * 136 + q * 8 + s * 32];

  float b2c[4];
#pragma unroll
  for (int c = 0; c < 4; ++c) b2c[c] = b2[c * 16 + l15];

  float sum4[4], sq4[4];
#pragma unroll
  for (int c = 0; c < 4; ++c) { sum4[c] = 0.f; sq4[c] = 0.f; }

  const int gw = blockIdx.x * 4 + wave;
  const int nw = gridDim.x * 4;

  for (int t = gw; t < kTiles3; t += nw) {
    const int r0 = t * 16;
    short8 af[4];
#pragma unroll
    for (int s = 0; s < 4; ++s)
      af[s] = *(const short8*)&agg2[(size_t)(r0 + l15) * 128 + q * 8 + s * 32];

    floatx4 acc[4];
#pragma unroll
    for (int c = 0; c < 4; ++c) {
      acc[c] = (floatx4){0.f, 0.f, 0.f, 0.f};
#pragma unroll
      for (int s = 0; s < 4; ++s)
        acc[c] = __builtin_amdgcn_mfma_f32_16x16x32_bf16(af[s], bfr[c][s], acc[c], 0, 0, 0);
    }
#pragma unroll
    for (int c = 0; c < 4; ++c) {
      int col = c * 16 + l15;
#pragma unroll
      for (int i = 0; i < 4; ++i) {
        float v = acc[c][i] + b2c[c];
        int row = r0 + q * 4 + i;
        pre2[(size_t)row * 64 + col] = v;
        sum4[c] += v; sq4[c] += v * v;
      }
    }
  }

  __syncthreads();
#pragma unroll
  for (int c = 0; c < 4; ++c) { redS[tid][c] = sum4[c]; redQ[tid][c] = sq4[c]; }
  __syncthreads();
  if (tid < 64) {
    int c = tid >> 4, r15 = tid & 15;
    float s = 0.f, qq = 0.f;
#pragma unroll
    for (int w = 0; w < 4; ++w)
#pragma unroll
      for (int p = 0; p < 4; ++p) {
        int T = w * 64 + p * 16 + r15;
        s += redS[T][c]; qq += redQ[T][c];
      }
    atomicAdd(&stats[S_SUM2 + tid], s);
    atomicAdd(&stats[S_SQ2 + tid], qq);
  }
}

// K5: BN2 finalize + embs = relu(BN2(pre2)); embsW = embs * Wd. Zeros out.
__global__ __launch_bounds__(256) void k5_embs(
    const float* __restrict__ pre2, const float* __restrict__ stats,
    const float* __restrict__ g2, const float* __restrict__ be2,
    const float* __restrict__ Wd, float* __restrict__ embs,
    float* __restrict__ embsW, float* __restrict__ out)
{
  __shared__ float sc[64], sh[64], wd[64];
  const int tid = threadIdx.x;
  if (blockIdx.x == 0 && tid == 0) out[0] = 0.f;
  if (tid < 64) {
    float mean = stats[S_SUM2 + tid] * (1.f / kN);
    float var  = stats[S_SQ2 + tid] * (1.f / kN) - mean * mean;
    float s    = g2[tid] * rsqrtf(var + kEps);
    sc[tid] = s; sh[tid] = be2[tid] - mean * s; wd[tid] = Wd[tid];
  }
  __syncthreads();
  int idx = blockIdx.x * 256 + tid;   // grid exact kN*64/256
  int col = idx & 63;
  float e = fmaxf(fmaf(pre2[idx], sc[col], sh[col]), 0.f);
  embs[idx] = e;
  embsW[idx] = e * wd[col];
}

// K6: quarter-wave (16 lanes) per pair. Coalesced 64B row reads, shfl_xor
// butterfly dot, block LDS reduce, one atomic per block.
__global__ __launch_bounds__(256) void k6_loss(
    const float* __restrict__ embs, const float* __restrict__ embsW,
    const int* __restrict__ tgt, const int* __restrict__ neg,
    const float* __restrict__ bd, float* __restrict__ out)
{
  __shared__ float redl[256];
  const int tid = threadIdx.x;
  const int tq = tid & 15;
  const int qb = tid >> 4;
  const float bd0 = bd[0];
  float lsum = 0.f;
  const int e0 = blockIdx.x * 128 + qb * 8;
#pragma unroll
  for (int it = 0; it < 8; ++it) {
    int e = e0 + it;
    if (e < 2 * kE) {
      int i, j; float lab;
      if (e < kE) { i = tgt[e];      j = tgt[kE + e]; lab = 1.f; }
      else        { i = neg[e - kE]; j = neg[e];      lab = 0.f; }
      float4 av = *(const float4*)(embsW + (size_t)i * 64 + tq * 4);
      float4 bv = *(const float4*)(embs  + (size_t)j * 64 + tq * 4);
      float p = av.x * bv.x + av.y * bv.y + av.z * bv.z + av.w * bv.w;
      p += __shfl_xor(p, 1); p += __shfl_xor(p, 2);
      p += __shfl_xor(p, 4); p += __shfl_xor(p, 8);
      p += bd0;
      float l = fmaxf(p, 0.f) - p * lab + log1pf(expf(-fabsf(p)));
      if (tq == 0) lsum += l;
    }
  }
  redl[tid] = lsum;
  __syncthreads();
  for (int s = 128; s > 0; s >>= 1) {
    if (tid < s) redl[tid] += redl[tid + s];
    __syncthreads();
  }
  if (tid == 0) atomicAdd(out, redl[0] * (1.f / (2 * kE)));
}

extern "C" void kernel_launch(void* const* d_in, const int* in_sizes, int n_in,
                              void* d_out, int out_size, void* d_ws, size_t ws_size,
                              hipStream_t stream) {
  (void)in_sizes; (void)n_in; (void)out_size; (void)ws_size;
  const float* x       = (const float*)d_in[0];
  const float* node_ts = (const float*)d_in[1];
  const int*   nidx    = (const int*)d_in[2];
  const float* nts     = (const float*)d_in[3];
  const int*   tgt     = (const int*)d_in[4];
  const int*   neg     = (const int*)d_in[5];
  const float* W1      = (const float*)d_in[6];
  const float* b1      = (const float*)d_in[7];
  const float* g1      = (const float*)d_in[8];
  const float* be1     = (const float*)d_in[9];
  const float* W2      = (const float*)d_in[10];
  const float* b2      = (const float*)d_in[11];
  const float* g2      = (const float*)d_in[12];
  const float* be2     = (const float*)d_in[13];
  const float* Wd      = (const float*)d_in[14];
  const float* bd      = (const float*)d_in[15];

  char* ws = (char*)d_ws;
  unsigned short* agg1 = (unsigned short*)ws;              // frag layout
  unsigned short* agg2 = (unsigned short*)(ws + OFF_AGG2);
  float* pre2  = (float*)(ws + OFF_PRE2);
  float* embs  = (float*)(ws + OFF_EMBS);
  float* embsW = (float*)(ws + OFF_EMBSW);
  float* stats = (float*)(ws + OFF_STATS);
  float* out   = (float*)d_out;

  k1a_gather<<<kM / 4, 256, 0, stream>>>(x, node_ts, nidx, nts, agg1, stats);
  k1s_stats<<<512, 256, 0, stream>>>(agg1, W1, b1, stats);
  k2_apply<<<kGroups, 256, 0, stream>>>(agg1, node_ts, nts, W1, b1, g1, be1,
                                        stats, (unsigned*)agg2);
  k3b_gemm2<<<160, 256, 0, stream>>>(agg2, W2, b2, stats, pre2);
  k5_embs<<<kN * 64 / 256, 256, 0, stream>>>(pre2, stats, g2, be2, Wd, embs,
                                             embsW, out);
  k6_loss<<<(2 * kE + 127) / 128, 256, 0, stream>>>(embs, embsW, tgt, neg, bd, out);
}

// Round 6
// 233.093 us; speedup vs baseline: 1.4270x; 1.4270x over previous
//
#include <hip/hip_runtime.h>
#include <math.h>

constexpr int kN = 20000;
constexpr int kD = 8;
constexpr int kE = 100000;
constexpr int kM = kN * 9;            // 180000 level-1 rows
constexpr int kTiles1 = kM / 16;      // 11250
constexpr int kTiles3 = kN / 16;      // 1250
constexpr int kGroups = kN / 16;      // 1250 groups of 16 nodes = 144 rows
constexpr float kEps = 1e-5f;

// stats float indices
constexpr int S_SUM1 = 0, S_SQ1 = 128, S_SUM2 = 256, S_SQ2 = 320;

// ws layout (bytes)
constexpr size_t OFF_AGG2  = 23040000;   // bf16 [kN][128] = 5.12 MB
constexpr size_t OFF_PRE2  = 28160000;   // f32 [kN][64]
constexpr size_t OFF_EMBS  = 33280000;
constexpr size_t OFF_EMBSW = 38400000;
constexpr size_t OFF_STATS = 43520000;   // 384 floats

typedef short short8 __attribute__((ext_vector_type(8)));
typedef float floatx4 __attribute__((ext_vector_type(4)));

__device__ __forceinline__ unsigned f2bf(float f) {  // f32 -> bf16 (RNE)
  unsigned u = __float_as_uint(f);
  u += 0x7fffu + ((u >> 16) & 1u);
  return u >> 16;
}

// ---------------------------------------------------------------------------
// K1a: one wave per level-1 row m. lane = feature. Masked-mean gather of 9
// x-rows; store agg1 bf16 in MFMA A-FRAGMENT order:
//   addr(m,k) = (m/16)*1024 + (k/8)*128 + (m%16)*8 + (k%8)   [shorts]
// Block 0 also zeros the stats block (consumed first by k1s, next kernel).
// ---------------------------------------------------------------------------
__global__ __launch_bounds__(256) void k1a_gather(
    const float* __restrict__ x, const float* __restrict__ node_ts,
    const int* __restrict__ nidx, const float* __restrict__ nts,
    unsigned short* __restrict__ agg1, float* __restrict__ stats)
{
  if (blockIdx.x == 0 && threadIdx.x < 384) stats[threadIdx.x] = 0.f;
  const int m = blockIdx.x * 4 + (threadIdx.x >> 6);
  const int lane = threadIdx.x & 63;
  const int n = (int)((unsigned)m / 9u);
  const int slot = m - n * 9;
  int c; float t;
  if (slot < kD) { c = nidx[n * kD + slot]; t = nts[n * kD + slot]; }
  else           { c = n;                   t = node_ts[n]; }
  c = __builtin_amdgcn_readfirstlane(c);
  float s = x[c * 64 + lane];
  float fcnt = 1.f;
#pragma unroll
  for (int j = 0; j < kD; ++j) {
    int cj = nidx[c * kD + j];
    float w = (nts[c * kD + j] <= t) ? 1.f : 0.f;
    s = fmaf(w, x[cj * 64 + lane], s);
    fcnt += w;
  }
  float v = s / fcnt;
  const int tt = m >> 4, r = m & 15, g = lane >> 3, jj = lane & 7;
  agg1[tt * 1024 + g * 128 + r * 8 + jj] = (unsigned short)f2bf(v);
}

// ---------------------------------------------------------------------------
// K1s: stats-only GEMM1 pass. MFMA over all tiles, accumulate column
// sum/sumsq of (acc + b1); NO pre1 store. Block LDS reduce, atomic per col.
// ---------------------------------------------------------------------------
__global__ __launch_bounds__(256, 3) void k1s_stats(
    const unsigned short* __restrict__ aggA,
    const float* __restrict__ W1, const float* __restrict__ b1,
    float* __restrict__ stats)
{
  __shared__ unsigned short W1T[128 * 72];
  __shared__ float redS[256][8];
  __shared__ float redQ[256][8];

  const int tid = threadIdx.x;
  const int lane = tid & 63;
  const int wave = tid >> 6;
  const int l15 = lane & 15;
  const int q = lane >> 4;

  for (int i = tid; i < 8192; i += 256) {
    int n = i >> 6, k = i & 63;
    W1T[n * 72 + k] = (unsigned short)f2bf(W1[k * 128 + n]);
  }
  __syncthreads();

  short8 bf[8][2];
#pragma unroll
  for (int c = 0; c < 8; ++c)
#pragma unroll
    for (int s = 0; s < 2; ++s)
      bf[c][s] = *(const short8*)&W1T[(c * 16 + l15) * 72 + q * 8 + s * 32];

  float b1c[8];
#pragma unroll
  for (int c = 0; c < 8; ++c) b1c[c] = b1[c * 16 + l15];

  float sum8[8], sq8[8];
#pragma unroll
  for (int c = 0; c < 8; ++c) { sum8[c] = 0.f; sq8[c] = 0.f; }

  const int gw = blockIdx.x * 4 + wave;
  const int nw = gridDim.x * 4;

  for (int t = gw; t < kTiles1; t += nw) {
    const unsigned short* ap = aggA + (size_t)t * 1024;
    short8 af0 = *(const short8*)(ap + q * 128 + l15 * 8);
    short8 af1 = *(const short8*)(ap + (4 + q) * 128 + l15 * 8);

    floatx4 acc[8];
#pragma unroll
    for (int c = 0; c < 8; ++c) {
      acc[c] = (floatx4){0.f, 0.f, 0.f, 0.f};
      acc[c] = __builtin_amdgcn_mfma_f32_16x16x32_bf16(af0, bf[c][0], acc[c], 0, 0, 0);
      acc[c] = __builtin_amdgcn_mfma_f32_16x16x32_bf16(af1, bf[c][1], acc[c], 0, 0, 0);
    }
#pragma unroll
    for (int c = 0; c < 8; ++c)
#pragma unroll
      for (int i = 0; i < 4; ++i) {
        float v = acc[c][i] + b1c[c];
        sum8[c] += v; sq8[c] += v * v;
      }
  }

  __syncthreads();
#pragma unroll
  for (int c = 0; c < 8; ++c) { redS[tid][c] = sum8[c]; redQ[tid][c] = sq8[c]; }
  __syncthreads();
  if (tid < 128) {
    int c = tid >> 4, r15 = tid & 15;
    float s = 0.f, qq = 0.f;
#pragma unroll
    for (int w = 0; w < 4; ++w)
#pragma unroll
      for (int p = 0; p < 4; ++p) {
        int T = w * 64 + p * 16 + r15;
        s += redS[T][c]; qq += redQ[T][c];
      }
    atomicAdd(&stats[S_SUM1 + tid], s);
    atomicAdd(&stats[S_SQ1 + tid], qq);
  }
}

// ---------------------------------------------------------------------------
// K2: apply pass, NO LDS ATOMICS (R5's 32-atomics/lane epilogue was the
// 138-us serialization). One block per 16-node group (144 rows = 9 tiles).
// Phase 1: waves t9-stride the 9 GEMM1 tiles, apply BN1+ReLU in C-frags,
//          store H[144][128] bf16 to LDS row-major (ds_write_b16).
// Phase 2 (after one barrier): wave w owns nodes 4w..4w+3; lane = dword-col;
//          weighted-sum 9 H rows per node from LDS (bank-free, 2-way alias),
//          divide by cnt, write agg2 coalesced. pre1 never touches HBM.
// ---------------------------------------------------------------------------
__global__ __launch_bounds__(256, 2) void k2_apply(
    const unsigned short* __restrict__ aggA, const float* __restrict__ node_ts,
    const float* __restrict__ nts, const float* __restrict__ W1,
    const float* __restrict__ b1, const float* __restrict__ g1,
    const float* __restrict__ be1, const float* __restrict__ stats,
    unsigned* __restrict__ agg2dw)
{
  __shared__ unsigned short W1T[128 * 72];   // 18.4 KB
  __shared__ unsigned short H[144 * 128];    // 36.9 KB relu'd layer-1 bf16
  __shared__ float sc[128], sh[128];
  __shared__ float wbuf[144];
  __shared__ float rvs[16];

  const int tid = threadIdx.x;
  const int lane = tid & 63;
  const int wave = tid >> 6;
  const int l15 = lane & 15;
  const int q = lane >> 4;
  const int g = blockIdx.x;          // group id, exact kGroups
  const int n0 = g * 16;

  for (int i = tid; i < 8192; i += 256) {
    int n = i >> 6, k = i & 63;
    W1T[n * 72 + k] = (unsigned short)f2bf(W1[k * 128 + n]);
  }
  if (tid < 128) {
    float mean = stats[S_SUM1 + tid] * (1.f / kM);
    float var  = stats[S_SQ1 + tid] * (1.f / kM) - mean * mean;
    float s    = g1[tid] * rsqrtf(var + kEps);
    sc[tid] = s; sh[tid] = be1[tid] - mean * s;
  }
  if (tid < 144) {
    int nd = n0 + tid / 9, slot = tid % 9;
    wbuf[tid] = (slot < kD) ? ((nts[nd * kD + slot] <= node_ts[nd]) ? 1.f : 0.f)
                            : 1.f;
  }
  __syncthreads();

  short8 bfr[8][2];
#pragma unroll
  for (int c = 0; c < 8; ++c)
#pragma unroll
    for (int s = 0; s < 2; ++s)
      bfr[c][s] = *(const short8*)&W1T[(c * 16 + l15) * 72 + q * 8 + s * 32];

  float scc[8], shc[8];
#pragma unroll
  for (int c = 0; c < 8; ++c) {
    int col = c * 16 + l15;
    scc[c] = sc[col];
    shc[c] = fmaf(b1[col], sc[col], sh[col]);   // fold bias into BN shift
  }
  if (tid < 16) {
    float s = 0.f;
#pragma unroll
    for (int j = 0; j < 9; ++j) s += wbuf[tid * 9 + j];
    rvs[tid] = 1.f / s;
  }

  // ---- phase 1: GEMM1 tiles -> BN1+ReLU -> H (LDS, row-major bf16) ----
  for (int t9 = wave; t9 < 9; t9 += 4) {
    const unsigned short* ap = aggA + (size_t)(g * 9 + t9) * 1024;
    short8 af0 = *(const short8*)(ap + q * 128 + l15 * 8);
    short8 af1 = *(const short8*)(ap + (4 + q) * 128 + l15 * 8);

    floatx4 acc[8];
#pragma unroll
    for (int c = 0; c < 8; ++c) {
      acc[c] = (floatx4){0.f, 0.f, 0.f, 0.f};
      acc[c] = __builtin_amdgcn_mfma_f32_16x16x32_bf16(af0, bfr[c][0], acc[c], 0, 0, 0);
      acc[c] = __builtin_amdgcn_mfma_f32_16x16x32_bf16(af1, bfr[c][1], acc[c], 0, 0, 0);
    }
#pragma unroll
    for (int i = 0; i < 4; ++i) {
      int lr = t9 * 16 + q * 4 + i;         // local row in [0,144)
#pragma unroll
      for (int c = 0; c < 8; ++c) {
        int col = c * 16 + l15;
        float h = fmaxf(fmaf(acc[c][i], scc[c], shc[c]), 0.f);
        H[lr * 128 + col] = (unsigned short)f2bf(h);
      }
    }
  }
  __syncthreads();

  // ---- phase 2: per-wave node ownership, register accumulation ----
  const unsigned* Hdw = (const unsigned*)H;
#pragma unroll
  for (int j = 0; j < 4; ++j) {
    int ndl = 4 * wave + j;                 // local node, wave-private
    float s0 = 0.f, s1 = 0.f;
#pragma unroll
    for (int slot = 0; slot < 9; ++slot) {
      int lr = ndl * 9 + slot;
      float w = wbuf[lr];
      unsigned u = Hdw[lr * 64 + lane];
      s0 = fmaf(w, __uint_as_float(u << 16), s0);
      s1 = fmaf(w, __uint_as_float(u & 0xffff0000u), s1);
    }
    float r = rvs[ndl];
    agg2dw[(size_t)(n0 + ndl) * 64 + lane] =
        f2bf(s0 * r) | (f2bf(s1 * r) << 16);
  }
}

// ---------------------------------------------------------------------------
// K3b: MFMA GEMM2: agg2 [N][128] x W2 [128][64] + b2 -> pre2 f32, BN2 stats.
// ---------------------------------------------------------------------------
__global__ __launch_bounds__(256, 3) void k3b_gemm2(
    const unsigned short* __restrict__ agg2, const float* __restrict__ W2,
    const float* __restrict__ b2, float* __restrict__ stats,
    float* __restrict__ pre2)
{
  __shared__ unsigned short W2T[64 * 136];
  __shared__ float redS[256][4];
  __shared__ float redQ[256][4];

  const int tid = threadIdx.x;
  const int lane = tid & 63;
  const int wave = tid >> 6;
  const int l15 = lane & 15;
  const int q = lane >> 4;

  for (int i = tid; i < 8192; i += 256) {
    int n = i >> 7, k = i & 127;
    W2T[n * 136 + k] = (unsigned short)f2bf(W2[k * 64 + n]);
  }
  __syncthreads();

  short8 bfr[4][4];
#pragma unroll
  for (int c = 0; c < 4; ++c)
#pragma unroll
    for (int s = 0; s < 4; ++s)
      bfr[c][s] = *(const short8*)&W2T[(c * 16 + l15) * 136 + q * 8 + s * 32];

  float b2c[4];
#pragma unroll
  for (int c = 0; c < 4; ++c) b2c[c] = b2[c * 16 + l15];

  float sum4[4], sq4[4];
#pragma unroll
  for (int c = 0; c < 4; ++c) { sum4[c] = 0.f; sq4[c] = 0.f; }

  const int gw = blockIdx.x * 4 + wave;
  const int nw = gridDim.x * 4;

  for (int t = gw; t < kTiles3; t += nw) {
    const int r0 = t * 16;
    short8 af[4];
#pragma unroll
    for (int s = 0; s < 4; ++s)
      af[s] = *(const short8*)&agg2[(size_t)(r0 + l15) * 128 + q * 8 + s * 32];

    floatx4 acc[4];
#pragma unroll
    for (int c = 0; c < 4; ++c) {
      acc[c] = (floatx4){0.f, 0.f, 0.f, 0.f};
#pragma unroll
      for (int s = 0; s < 4; ++s)
        acc[c] = __builtin_amdgcn_mfma_f32_16x16x32_bf16(af[s], bfr[c][s], acc[c], 0, 0, 0);
    }
#pragma unroll
    for (int c = 0; c < 4; ++c) {
      int col = c * 16 + l15;
#pragma unroll
      for (int i = 0; i < 4; ++i) {
        float v = acc[c][i] + b2c[c];
        int row = r0 + q * 4 + i;
        pre2[(size_t)row * 64 + col] = v;
        sum4[c] += v; sq4[c] += v * v;
      }
    }
  }

  __syncthreads();
#pragma unroll
  for (int c = 0; c < 4; ++c) { redS[tid][c] = sum4[c]; redQ[tid][c] = sq4[c]; }
  __syncthreads();
  if (tid < 64) {
    int c = tid >> 4, r15 = tid & 15;
    float s = 0.f, qq = 0.f;
#pragma unroll
    for (int w = 0; w < 4; ++w)
#pragma unroll
      for (int p = 0; p < 4; ++p) {
        int T = w * 64 + p * 16 + r15;
        s += redS[T][c]; qq += redQ[T][c];
      }
    atomicAdd(&stats[S_SUM2 + tid], s);
    atomicAdd(&stats[S_SQ2 + tid], qq);
  }
}

// K5: BN2 finalize + embs = relu(BN2(pre2)); embsW = embs * Wd. Zeros out.
__global__ __launch_bounds__(256) void k5_embs(
    const float* __restrict__ pre2, const float* __restrict__ stats,
    const float* __restrict__ g2, const float* __restrict__ be2,
    const float* __restrict__ Wd, float* __restrict__ embs,
    float* __restrict__ embsW, float* __restrict__ out)
{
  __shared__ float sc[64], sh[64], wd[64];
  const int tid = threadIdx.x;
  if (blockIdx.x == 0 && tid == 0) out[0] = 0.f;
  if (tid < 64) {
    float mean = stats[S_SUM2 + tid] * (1.f / kN);
    float var  = stats[S_SQ2 + tid] * (1.f / kN) - mean * mean;
    float s    = g2[tid] * rsqrtf(var + kEps);
    sc[tid] = s; sh[tid] = be2[tid] - mean * s; wd[tid] = Wd[tid];
  }
  __syncthreads();
  int idx = blockIdx.x * 256 + tid;   // grid exact kN*64/256
  int col = idx & 63;
  float e = fmaxf(fmaf(pre2[idx], sc[col], sh[col]), 0.f);
  embs[idx] = e;
  embsW[idx] = e * wd[col];
}

// K6: quarter-wave (16 lanes) per pair. Coalesced 64B row reads, shfl_xor
// butterfly dot, block LDS reduce, one atomic per block.
__global__ __launch_bounds__(256) void k6_loss(
    const float* __restrict__ embs, const float* __restrict__ embsW,
    const int* __restrict__ tgt, const int* __restrict__ neg,
    const float* __restrict__ bd, float* __restrict__ out)
{
  __shared__ float redl[256];
  const int tid = threadIdx.x;
  const int tq = tid & 15;
  const int qb = tid >> 4;
  const float bd0 = bd[0];
  float lsum = 0.f;
  const int e0 = blockIdx.x * 128 + qb * 8;
#pragma unroll
  for (int it = 0; it < 8; ++it) {
    int e = e0 + it;
    if (e < 2 * kE) {
      int i, j; float lab;
      if (e < kE) { i = tgt[e];      j = tgt[kE + e]; lab = 1.f; }
      else        { i = neg[e - kE]; j = neg[e];      lab = 0.f; }
      float4 av = *(const float4*)(embsW + (size_t)i * 64 + tq * 4);
      float4 bv = *(const float4*)(embs  + (size_t)j * 64 + tq * 4);
      float p = av.x * bv.x + av.y * bv.y + av.z * bv.z + av.w * bv.w;
      p += __shfl_xor(p, 1); p += __shfl_xor(p, 2);
      p += __shfl_xor(p, 4); p += __shfl_xor(p, 8);
      p += bd0;
      float l = fmaxf(p, 0.f) - p * lab + log1pf(expf(-fabsf(p)));
      if (tq == 0) lsum += l;
    }
  }
  redl[tid] = lsum;
  __syncthreads();
  for (int s = 128; s > 0; s >>= 1) {
    if (tid < s) redl[tid] += redl[tid + s];
    __syncthreads();
  }
  if (tid == 0) atomicAdd(out, redl[0] * (1.f / (2 * kE)));
}

extern "C" void kernel_launch(void* const* d_in, const int* in_sizes, int n_in,
                              void* d_out, int out_size, void* d_ws, size_t ws_size,
                              hipStream_t stream) {
  (void)in_sizes; (void)n_in; (void)out_size; (void)ws_size;
  const float* x       = (const float*)d_in[0];
  const float* node_ts = (const float*)d_in[1];
  const int*   nidx    = (const int*)d_in[2];
  const float* nts     = (const float*)d_in[3];
  const int*   tgt     = (const int*)d_in[4];
  const int*   neg     = (const int*)d_in[5];
  const float* W1      = (const float*)d_in[6];
  const float* b1      = (const float*)d_in[7];
  const float* g1      = (const float*)d_in[8];
  const float* be1     = (const float*)d_in[9];
  const float* W2      = (const float*)d_in[10];
  const float* b2      = (const float*)d_in[11];
  const float* g2      = (const float*)d_in[12];
  const float* be2     = (const float*)d_in[13];
  const float* Wd      = (const float*)d_in[14];
  const float* bd      = (const float*)d_in[15];

  char* ws = (char*)d_ws;
  unsigned short* agg1 = (unsigned short*)ws;              // frag layout
  unsigned short* agg2 = (unsigned short*)(ws + OFF_AGG2);
  float* pre2  = (float*)(ws + OFF_PRE2);
  float* embs  = (float*)(ws + OFF_EMBS);
  float* embsW = (float*)(ws + OFF_EMBSW);
  float* stats = (float*)(ws + OFF_STATS);
  float* out   = (float*)d_out;

  k1a_gather<<<kM / 4, 256, 0, stream>>>(x, node_ts, nidx, nts, agg1, stats);
  k1s_stats<<<512, 256, 0, stream>>>(agg1, W1, b1, stats);
  k2_apply<<<kGroups, 256, 0, stream>>>(agg1, node_ts, nts, W1, b1, g1, be1,
                                        stats, (unsigned*)agg2);
  k3b_gemm2<<<160, 256, 0, stream>>>(agg2, W2, b2, stats, pre2);
  k5_embs<<<kN * 64 / 256, 256, 0, stream>>>(pre2, stats, g2, be2, Wd, embs,
                                             embsW, out);
  k6_loss<<<(2 * kE + 127) / 128, 256, 0, stream>>>(embs, embsW, tgt, neg, bd, out);
}

// Round 7
// 228.642 us; speedup vs baseline: 1.4548x; 1.0195x over previous
//
#include <hip/hip_runtime.h>
#include <math.h>

constexpr int kN = 20000;
constexpr int kD = 8;
constexpr int kE = 100000;
constexpr int kM = kN * 9;            // 180000 level-1 rows
constexpr int kTiles1 = kM / 16;      // 11250
constexpr int kTiles3 = kN / 16;      // 1250
constexpr int kGroups = kN / 16;      // 1250 groups of 16 nodes = 144 rows
constexpr float kEps = 1e-5f;

// stats float indices
constexpr int S_SUM1 = 0, S_SQ1 = 128, S_SUM2 = 256, S_SQ2 = 320;

// ws layout (bytes). agg1 frag bf16 [kM][64] = 23.04 MB at 0.
// meanp bf16 [kN][9][64] = 23.04 MB at 23.04 MB; dead after kB_rows, so
// agg2 (written later by k2) aliases its first 5.12 MB. Peak 43.5 MB.
constexpr size_t OFF_MEANP = 23040000;
constexpr size_t OFF_AGG2  = 23040000;   // aliases dead meanp
constexpr size_t OFF_PRE2  = 28160000;   // f32 [kN][64]
constexpr size_t OFF_EMBS  = 33280000;
constexpr size_t OFF_EMBSW = 38400000;
constexpr size_t OFF_STATS = 43520000;   // 384 floats

typedef short short8 __attribute__((ext_vector_type(8)));
typedef float floatx4 __attribute__((ext_vector_type(4)));

__device__ __forceinline__ unsigned f2bf(float f) {  // f32 -> bf16 (RNE)
  unsigned u = __float_as_uint(f);
  u += 0x7fffu + ((u >> 16) & 1u);
  return u >> 16;
}

// ---------------------------------------------------------------------------
// K0: sorted-prefix means, one wave per node c (4 waves/block). For node c
// with neighbor ts t_0..t_7 (stable ranks), mean_k = (x[c] + sum of the k
// smallest-ts neighbors) / (k+1), k=0..8. Every level-1 masked mean equals
// meanp[c][rank] where rank = #{j: t_j <= t_query} -> 9x gather dedupe vs
// per-row gathering (415 MB -> 46 MB). Block 0 zeros the stats block.
// ---------------------------------------------------------------------------
__global__ __launch_bounds__(256) void k0_prefix(
    const float* __restrict__ x, const int* __restrict__ nidx,
    const float* __restrict__ nts, unsigned short* __restrict__ meanp,
    float* __restrict__ stats)
{
  if (blockIdx.x == 0 && threadIdx.x < 384) stats[threadIdx.x] = 0.f;
  const int c = blockIdx.x * 4 + (threadIdx.x >> 6);   // grid exact kN/4
  const int lane = threadIdx.x & 63;

  float tsv[8]; int idxv[8];
#pragma unroll
  for (int j = 0; j < 8; ++j) {
    tsv[j] = nts[c * 8 + j];
    idxv[j] = nidx[c * 8 + j];
  }
  // stable rank of each neighbor by ts
  int rank[8];
#pragma unroll
  for (int j = 0; j < 8; ++j) {
    int r = 0;
#pragma unroll
    for (int j2 = 0; j2 < 8; ++j2)
      r += (tsv[j2] < tsv[j] || (tsv[j2] == tsv[j] && j2 < j)) ? 1 : 0;
    rank[j] = r;
  }
  // ord[k] = neighbor index with rank k
  int ord[8];
#pragma unroll
  for (int k = 0; k < 8; ++k) {
    int js = 0;
#pragma unroll
    for (int j = 0; j < 8; ++j) if (rank[j] == k) js = j;
    ord[k] = idxv[js];
  }

  float acc = x[c * 64 + lane];
  unsigned short* mp = meanp + (size_t)c * 576 + lane;
  mp[0] = (unsigned short)f2bf(acc);               // k=0: /1
#pragma unroll
  for (int k = 0; k < 8; ++k) {
    acc += x[ord[k] * 64 + lane];
    mp[(k + 1) * 64] = (unsigned short)f2bf(acc / (float)(k + 2));
  }
}

// ---------------------------------------------------------------------------
// KB: build agg1 (MFMA A-frag layout) — one wave per node n writes its 9
// level-1 rows. Per slot: child c, query t, rank = #{ts_j <= t}, then copy
// meanp[c][rank][lane]. Zero arithmetic on the features.
//   frag addr(m,k) = (m/16)*1024 + (k/8)*128 + (m%16)*8 + (k%8) [shorts]
// ---------------------------------------------------------------------------
__global__ __launch_bounds__(256) void kB_rows(
    const float* __restrict__ node_ts, const int* __restrict__ nidx,
    const float* __restrict__ nts, const unsigned short* __restrict__ meanp,
    unsigned short* __restrict__ agg1)
{
  const int n = blockIdx.x * 4 + (threadIdx.x >> 6);   // grid exact kN/4
  const int lane = threadIdx.x & 63;
  const float tn = node_ts[n];
  const int g = lane >> 3, jj = lane & 7;
#pragma unroll
  for (int s = 0; s < 9; ++s) {
    int c; float t;
    if (s < 8) { c = nidx[n * 8 + s]; t = nts[n * 8 + s]; }
    else       { c = n;               t = tn; }
    int rank = 0;
#pragma unroll
    for (int j = 0; j < 8; ++j) rank += (nts[c * 8 + j] <= t) ? 1 : 0;
    unsigned short v = meanp[(size_t)c * 576 + rank * 64 + lane];
    int m = n * 9 + s;
    int tt = m >> 4, r = m & 15;
    agg1[tt * 1024 + g * 128 + r * 8 + jj] = v;
  }
}

// ---------------------------------------------------------------------------
// K1s: stats-only GEMM1 pass. MFMA over all tiles, accumulate column
// sum/sumsq of (acc + b1); NO pre1 store. Block LDS reduce, atomic per col.
// ---------------------------------------------------------------------------
__global__ __launch_bounds__(256, 3) void k1s_stats(
    const unsigned short* __restrict__ aggA,
    const float* __restrict__ W1, const float* __restrict__ b1,
    float* __restrict__ stats)
{
  __shared__ unsigned short W1T[128 * 72];
  __shared__ float redS[256][8];
  __shared__ float redQ[256][8];

  const int tid = threadIdx.x;
  const int lane = tid & 63;
  const int wave = tid >> 6;
  const int l15 = lane & 15;
  const int q = lane >> 4;

  for (int i = tid; i < 8192; i += 256) {
    int n = i >> 6, k = i & 63;
    W1T[n * 72 + k] = (unsigned short)f2bf(W1[k * 128 + n]);
  }
  __syncthreads();

  short8 bf[8][2];
#pragma unroll
  for (int c = 0; c < 8; ++c)
#pragma unroll
    for (int s = 0; s < 2; ++s)
      bf[c][s] = *(const short8*)&W1T[(c * 16 + l15) * 72 + q * 8 + s * 32];

  float b1c[8];
#pragma unroll
  for (int c = 0; c < 8; ++c) b1c[c] = b1[c * 16 + l15];

  float sum8[8], sq8[8];
#pragma unroll
  for (int c = 0; c < 8; ++c) { sum8[c] = 0.f; sq8[c] = 0.f; }

  const int gw = blockIdx.x * 4 + wave;
  const int nw = gridDim.x * 4;

  for (int t = gw; t < kTiles1; t += nw) {
    const unsigned short* ap = aggA + (size_t)t * 1024;
    short8 af0 = *(const short8*)(ap + q * 128 + l15 * 8);
    short8 af1 = *(const short8*)(ap + (4 + q) * 128 + l15 * 8);

    floatx4 acc[8];
#pragma unroll
    for (int c = 0; c < 8; ++c) {
      acc[c] = (floatx4){0.f, 0.f, 0.f, 0.f};
      acc[c] = __builtin_amdgcn_mfma_f32_16x16x32_bf16(af0, bf[c][0], acc[c], 0, 0, 0);
      acc[c] = __builtin_amdgcn_mfma_f32_16x16x32_bf16(af1, bf[c][1], acc[c], 0, 0, 0);
    }
#pragma unroll
    for (int c = 0; c < 8; ++c)
#pragma unroll
      for (int i = 0; i < 4; ++i) {
        float v = acc[c][i] + b1c[c];
        sum8[c] += v; sq8[c] += v * v;
      }
  }

  __syncthreads();
#pragma unroll
  for (int c = 0; c < 8; ++c) { redS[tid][c] = sum8[c]; redQ[tid][c] = sq8[c]; }
  __syncthreads();
  if (tid < 128) {
    int c = tid >> 4, r15 = tid & 15;
    float s = 0.f, qq = 0.f;
#pragma unroll
    for (int w = 0; w < 4; ++w)
#pragma unroll
      for (int p = 0; p < 4; ++p) {
        int T = w * 64 + p * 16 + r15;
        s += redS[T][c]; qq += redQ[T][c];
      }
    atomicAdd(&stats[S_SUM1 + tid], s);
    atomicAdd(&stats[S_SQ1 + tid], qq);
  }
}

// ---------------------------------------------------------------------------
// K2: apply pass, no LDS atomics. One block per 16-node group (144 rows =
// 9 tiles). Phase 1: GEMM1 + BN1+ReLU -> H[144][128] bf16 in LDS.
// Phase 2: wave w owns nodes 4w..4w+3, weighted-sum 9 rows/node from LDS,
// divide, write agg2. pre1 never touches HBM.
// ---------------------------------------------------------------------------
__global__ __launch_bounds__(256, 2) void k2_apply(
    const unsigned short* __restrict__ aggA, const float* __restrict__ node_ts,
    const float* __restrict__ nts, const float* __restrict__ W1,
    const float* __restrict__ b1, const float* __restrict__ g1,
    const float* __restrict__ be1, const float* __restrict__ stats,
    unsigned* __restrict__ agg2dw)
{
  __shared__ unsigned short W1T[128 * 72];   // 18.4 KB
  __shared__ unsigned short H[144 * 128];    // 36.9 KB relu'd layer-1 bf16
  __shared__ float sc[128], sh[128];
  __shared__ float wbuf[144];
  __shared__ float rvs[16];

  const int tid = threadIdx.x;
  const int lane = tid & 63;
  const int wave = tid >> 6;
  const int l15 = lane & 15;
  const int q = lane >> 4;
  const int g = blockIdx.x;          // group id, exact kGroups
  const int n0 = g * 16;

  for (int i = tid; i < 8192; i += 256) {
    int n = i >> 6, k = i & 63;
    W1T[n * 72 + k] = (unsigned short)f2bf(W1[k * 128 + n]);
  }
  if (tid < 128) {
    float mean = stats[S_SUM1 + tid] * (1.f / kM);
    float var  = stats[S_SQ1 + tid] * (1.f / kM) - mean * mean;
    float s    = g1[tid] * rsqrtf(var + kEps);
    sc[tid] = s; sh[tid] = be1[tid] - mean * s;
  }
  if (tid < 144) {
    int nd = n0 + tid / 9, slot = tid % 9;
    wbuf[tid] = (slot < kD) ? ((nts[nd * kD + slot] <= node_ts[nd]) ? 1.f : 0.f)
                            : 1.f;
  }
  __syncthreads();

  short8 bfr[8][2];
#pragma unroll
  for (int c = 0; c < 8; ++c)
#pragma unroll
    for (int s = 0; s < 2; ++s)
      bfr[c][s] = *(const short8*)&W1T[(c * 16 + l15) * 72 + q * 8 + s * 32];

  float scc[8], shc[8];
#pragma unroll
  for (int c = 0; c < 8; ++c) {
    int col = c * 16 + l15;
    scc[c] = sc[col];
    shc[c] = fmaf(b1[col], sc[col], sh[col]);   // fold bias into BN shift
  }
  if (tid < 16) {
    float s = 0.f;
#pragma unroll
    for (int j = 0; j < 9; ++j) s += wbuf[tid * 9 + j];
    rvs[tid] = 1.f / s;
  }

  // ---- phase 1: GEMM1 tiles -> BN1+ReLU -> H (LDS, row-major bf16) ----
  for (int t9 = wave; t9 < 9; t9 += 4) {
    const unsigned short* ap = aggA + (size_t)(g * 9 + t9) * 1024;
    short8 af0 = *(const short8*)(ap + q * 128 + l15 * 8);
    short8 af1 = *(const short8*)(ap + (4 + q) * 128 + l15 * 8);

    floatx4 acc[8];
#pragma unroll
    for (int c = 0; c < 8; ++c) {
      acc[c] = (floatx4){0.f, 0.f, 0.f, 0.f};
      acc[c] = __builtin_amdgcn_mfma_f32_16x16x32_bf16(af0, bfr[c][0], acc[c], 0, 0, 0);
      acc[c] = __builtin_amdgcn_mfma_f32_16x16x32_bf16(af1, bfr[c][1], acc[c], 0, 0, 0);
    }
#pragma unroll
    for (int i = 0; i < 4; ++i) {
      int lr = t9 * 16 + q * 4 + i;         // local row in [0,144)
#pragma unroll
      for (int c = 0; c < 8; ++c) {
        int col = c * 16 + l15;
        float h = fmaxf(fmaf(acc[c][i], scc[c], shc[c]), 0.f);
        H[lr * 128 + col] = (unsigned short)f2bf(h);
      }
    }
  }
  __syncthreads();

  // ---- phase 2: per-wave node ownership, register accumulation ----
  const unsigned* Hdw = (const unsigned*)H;
#pragma unroll
  for (int j = 0; j < 4; ++j) {
    int ndl = 4 * wave + j;                 // local node, wave-private
    float s0 = 0.f, s1 = 0.f;
#pragma unroll
    for (int slot = 0; slot < 9; ++slot) {
      int lr = ndl * 9 + slot;
      float w = wbuf[lr];
      unsigned u = Hdw[lr * 64 + lane];
      s0 = fmaf(w, __uint_as_float(u << 16), s0);
      s1 = fmaf(w, __uint_as_float(u & 0xffff0000u), s1);
    }
    float r = rvs[ndl];
    agg2dw[(size_t)(n0 + ndl) * 64 + lane] =
        f2bf(s0 * r) | (f2bf(s1 * r) << 16);
  }
}

// ---------------------------------------------------------------------------
// K3b: MFMA GEMM2: agg2 [N][128] x W2 [128][64] + b2 -> pre2 f32, BN2 stats.
// ---------------------------------------------------------------------------
__global__ __launch_bounds__(256, 3) void k3b_gemm2(
    const unsigned short* __restrict__ agg2, const float* __restrict__ W2,
    const float* __restrict__ b2, float* __restrict__ stats,
    float* __restrict__ pre2)
{
  __shared__ unsigned short W2T[64 * 136];
  __shared__ float redS[256][4];
  __shared__ float redQ[256][4];

  const int tid = threadIdx.x;
  const int lane = tid & 63;
  const int wave = tid >> 6;
  const int l15 = lane & 15;
  const int q = lane >> 4;

  for (int i = tid; i < 8192; i += 256) {
    int n = i >> 7, k = i & 127;
    W2T[n * 136 + k] = (unsigned short)f2bf(W2[k * 64 + n]);
  }
  __syncthreads();

  short8 bfr[4][4];
#pragma unroll
  for (int c = 0; c < 4; ++c)
#pragma unroll
    for (int s = 0; s < 4; ++s)
      bfr[c][s] = *(const short8*)&W2T[(c * 16 + l15) * 136 + q * 8 + s * 32];

  float b2c[4];
#pragma unroll
  for (int c = 0; c < 4; ++c) b2c[c] = b2[c * 16 + l15];

  float sum4[4], sq4[4];
#pragma unroll
  for (int c = 0; c < 4; ++c) { sum4[c] = 0.f; sq4[c] = 0.f; }

  const int gw = blockIdx.x * 4 + wave;
  const int nw = gridDim.x * 4;

  for (int t = gw; t < kTiles3; t += nw) {
    const int r0 = t * 16;
    short8 af[4];
#pragma unroll
    for (int s = 0; s < 4; ++s)
      af[s] = *(const short8*)&agg2[(size_t)(r0 + l15) * 128 + q * 8 + s * 32];

    floatx4 acc[4];
#pragma unroll
    for (int c = 0; c < 4; ++c) {
      acc[c] = (floatx4){0.f, 0.f, 0.f, 0.f};
#pragma unroll
      for (int s = 0; s < 4; ++s)
        acc[c] = __builtin_amdgcn_mfma_f32_16x16x32_bf16(af[s], bfr[c][s], acc[c], 0, 0, 0);
    }
#pragma unroll
    for (int c = 0; c < 4; ++c) {
      int col = c * 16 + l15;
#pragma unroll
      for (int i = 0; i < 4; ++i) {
        float v = acc[c][i] + b2c[c];
        int row = r0 + q * 4 + i;
        pre2[(size_t)row * 64 + col] = v;
        sum4[c] += v; sq4[c] += v * v;
      }
    }
  }

  __syncthreads();
#pragma unroll
  for (int c = 0; c < 4; ++c) { redS[tid][c] = sum4[c]; redQ[tid][c] = sq4[c]; }
  __syncthreads();
  if (tid < 64) {
    int c = tid >> 4, r15 = tid & 15;
    float s = 0.f, qq = 0.f;
#pragma unroll
    for (int w = 0; w < 4; ++w)
#pragma unroll
      for (int p = 0; p < 4; ++p) {
        int T = w * 64 + p * 16 + r15;
        s += redS[T][c]; qq += redQ[T][c];
      }
    atomicAdd(&stats[S_SUM2 + tid], s);
    atomicAdd(&stats[S_SQ2 + tid], qq);
  }
}

// K5: BN2 finalize + embs = relu(BN2(pre2)); embsW = embs * Wd. Zeros out.
__global__ __launch_bounds__(256) void k5_embs(
    const float* __restrict__ pre2, const float* __restrict__ stats,
    const float* __restrict__ g2, const float* __restrict__ be2,
    const float* __restrict__ Wd, float* __restrict__ embs,
    float* __restrict__ embsW, float* __restrict__ out)
{
  __shared__ float sc[64], sh[64], wd[64];
  const int tid = threadIdx.x;
  if (blockIdx.x == 0 && tid == 0) out[0] = 0.f;
  if (tid < 64) {
    float mean = stats[S_SUM2 + tid] * (1.f / kN);
    float var  = stats[S_SQ2 + tid] * (1.f / kN) - mean * mean;
    float s    = g2[tid] * rsqrtf(var + kEps);
    sc[tid] = s; sh[tid] = be2[tid] - mean * s; wd[tid] = Wd[tid];
  }
  __syncthreads();
  int idx = blockIdx.x * 256 + tid;   // grid exact kN*64/256
  int col = idx & 63;
  float e = fmaxf(fmaf(pre2[idx], sc[col], sh[col]), 0.f);
  embs[idx] = e;
  embsW[idx] = e * wd[col];
}

// K6: quarter-wave (16 lanes) per pair. Coalesced 64B row reads, shfl_xor
// butterfly dot, block LDS reduce, one atomic per block.
__global__ __launch_bounds__(256) void k6_loss(
    const float* __restrict__ embs, const float* __restrict__ embsW,
    const int* __restrict__ tgt, const int* __restrict__ neg,
    const float* __restrict__ bd, float* __restrict__ out)
{
  __shared__ float redl[256];
  const int tid = threadIdx.x;
  const int tq = tid & 15;
  const int qb = tid >> 4;
  const float bd0 = bd[0];
  float lsum = 0.f;
  const int e0 = blockIdx.x * 128 + qb * 8;
#pragma unroll
  for (int it = 0; it < 8; ++it) {
    int e = e0 + it;
    if (e < 2 * kE) {
      int i, j; float lab;
      if (e < kE) { i = tgt[e];      j = tgt[kE + e]; lab = 1.f; }
      else        { i = neg[e - kE]; j = neg[e];      lab = 0.f; }
      float4 av = *(const float4*)(embsW + (size_t)i * 64 + tq * 4);
      float4 bv = *(const float4*)(embs  + (size_t)j * 64 + tq * 4);
      float p = av.x * bv.x + av.y * bv.y + av.z * bv.z + av.w * bv.w;
      p += __shfl_xor(p, 1); p += __shfl_xor(p, 2);
      p += __shfl_xor(p, 4); p += __shfl_xor(p, 8);
      p += bd0;
      float l = fmaxf(p, 0.f) - p * lab + log1pf(expf(-fabsf(p)));
      if (tq == 0) lsum += l;
    }
  }
  redl[tid] = lsum;
  __syncthreads();
  for (int s = 128; s > 0; s >>= 1) {
    if (tid < s) redl[tid] += redl[tid + s];
    __syncthreads();
  }
  if (tid == 0) atomicAdd(out, redl[0] * (1.f / (2 * kE)));
}

extern "C" void kernel_launch(void* const* d_in, const int* in_sizes, int n_in,
                              void* d_out, int out_size, void* d_ws, size_t ws_size,
                              hipStream_t stream) {
  (void)in_sizes; (void)n_in; (void)out_size; (void)ws_size;
  const float* x       = (const float*)d_in[0];
  const float* node_ts = (const float*)d_in[1];
  const int*   nidx    = (const int*)d_in[2];
  const float* nts     = (const float*)d_in[3];
  const int*   tgt     = (const int*)d_in[4];
  const int*   neg     = (const int*)d_in[5];
  const float* W1      = (const float*)d_in[6];
  const float* b1      = (const float*)d_in[7];
  const float* g1      = (const float*)d_in[8];
  const float* be1     = (const float*)d_in[9];
  const float* W2      = (const float*)d_in[10];
  const float* b2      = (const float*)d_in[11];
  const float* g2      = (const float*)d_in[12];
  const float* be2     = (const float*)d_in[13];
  const float* Wd      = (const float*)d_in[14];
  const float* bd      = (const float*)d_in[15];

  char* ws = (char*)d_ws;
  unsigned short* agg1  = (unsigned short*)ws;               // frag layout
  unsigned short* meanp = (unsigned short*)(ws + OFF_MEANP); // [kN][9][64]
  unsigned short* agg2  = (unsigned short*)(ws + OFF_AGG2);  // aliases dead meanp
  float* pre2  = (float*)(ws + OFF_PRE2);
  float* embs  = (float*)(ws + OFF_EMBS);
  float* embsW = (float*)(ws + OFF_EMBSW);
  float* stats = (float*)(ws + OFF_STATS);
  float* out   = (float*)d_out;

  k0_prefix<<<kN / 4, 256, 0, stream>>>(x, nidx, nts, meanp, stats);
  kB_rows<<<kN / 4, 256, 0, stream>>>(node_ts, nidx, nts, meanp, agg1);
  k1s_stats<<<512, 256, 0, stream>>>(agg1, W1, b1, stats);
  k2_apply<<<kGroups, 256, 0, stream>>>(agg1, node_ts, nts, W1, b1, g1, be1,
                                        stats, (unsigned*)agg2);
  k3b_gemm2<<<160, 256, 0, stream>>>(agg2, W2, b2, stats, pre2);
  k5_embs<<<kN * 64 / 256, 256, 0, stream>>>(pre2, stats, g2, be2, Wd, embs,
                                             embsW, out);
  k6_loss<<<(2 * kE + 127) / 128, 256, 0, stream>>>(embs, embsW, tgt, neg, bd, out);
}

// Round 8
// 223.076 us; speedup vs baseline: 1.4911x; 1.0249x over previous
//
#include <hip/hip_runtime.h>
#include <math.h>

constexpr int kN = 20000;
constexpr int kD = 8;
constexpr int kE = 100000;
constexpr int kM = kN * 9;            // 180000 level-1 rows
constexpr int kTiles1 = kM / 16;      // 11250
constexpr int kTiles3 = kN / 16;      // 1250
constexpr int kGroups = kN / 16;      // 1250 groups of 16 nodes = 144 rows
constexpr float kEps = 1e-5f;

// stats float indices
constexpr int S_SUM1 = 0, S_SQ1 = 128, S_SUM2 = 256, S_SQ2 = 320;

// ws layout (bytes). meanp bf16 [kN][9][64] = 23.04 MB at 0 (no agg1 any
// more — A-frags are gathered straight from meanp via rowidx).
constexpr size_t OFF_AGG2   = 23040000;  // bf16 [kN][128] = 5.12 MB
constexpr size_t OFF_PRE2   = 28160000;  // f32 [kN][64]
constexpr size_t OFF_EMBS   = 33280000;
constexpr size_t OFF_EMBSW  = 38400000;
constexpr size_t OFF_STATS  = 43520000;  // 384 floats
constexpr size_t OFF_ROWIDX = 43524096;  // int [kM] = 720 KB

typedef short short8 __attribute__((ext_vector_type(8)));
typedef float floatx4 __attribute__((ext_vector_type(4)));

__device__ __forceinline__ unsigned f2bf(float f) {  // f32 -> bf16 (RNE)
  unsigned u = __float_as_uint(f);
  u += 0x7fffu + ((u >> 16) & 1u);
  return u >> 16;
}

// ---------------------------------------------------------------------------
// KA: one wave per node c. (1) stable-rank c's 8 neighbor ts, accumulate x
// rows in sorted order -> 9 prefix means meanp[c][0..8][64] bf16 (every
// level-1 masked mean equals one of these). (2) lanes 0..8: for node c as
// PARENT, slot s: child cc, query t, rank = #{ts_j(cc) <= t}; rowidx[c*9+s]
// = cc*9+rank. Block 0 zeros the stats block.
// ---------------------------------------------------------------------------
__global__ __launch_bounds__(256) void kA_prep(
    const float* __restrict__ x, const float* __restrict__ node_ts,
    const int* __restrict__ nidx, const float* __restrict__ nts,
    unsigned short* __restrict__ meanp, int* __restrict__ rowidx,
    float* __restrict__ stats)
{
  if (blockIdx.x == 0 && threadIdx.x < 384) stats[threadIdx.x] = 0.f;
  const int c = blockIdx.x * 4 + (threadIdx.x >> 6);   // grid exact kN/4
  const int lane = threadIdx.x & 63;

  float tsv[8]; int idxv[8];
#pragma unroll
  for (int j = 0; j < 8; ++j) {
    tsv[j] = nts[c * 8 + j];
    idxv[j] = nidx[c * 8 + j];
  }
  // stable rank of each neighbor by ts
  int rank[8];
#pragma unroll
  for (int j = 0; j < 8; ++j) {
    int r = 0;
#pragma unroll
    for (int j2 = 0; j2 < 8; ++j2)
      r += (tsv[j2] < tsv[j] || (tsv[j2] == tsv[j] && j2 < j)) ? 1 : 0;
    rank[j] = r;
  }
  // ord[k] = neighbor index with rank k
  int ord[8];
#pragma unroll
  for (int k = 0; k < 8; ++k) {
    int js = 0;
#pragma unroll
    for (int j = 0; j < 8; ++j) if (rank[j] == k) js = j;
    ord[k] = idxv[js];
  }

  float acc = x[c * 64 + lane];
  unsigned short* mp = meanp + (size_t)c * 576 + lane;
  mp[0] = (unsigned short)f2bf(acc);               // k=0: /1
#pragma unroll
  for (int k = 0; k < 8; ++k) {
    acc += x[ord[k] * 64 + lane];
    mp[(k + 1) * 64] = (unsigned short)f2bf(acc / (float)(k + 2));
  }

  // rowidx for node c as parent
  if (lane < 9) {
    int cc; float t;
    if (lane < 8) { cc = idxv[lane]; t = tsv[lane]; }
    else          { cc = c;          t = node_ts[c]; }
    int r = 0;
    if (lane < 8) {
#pragma unroll
      for (int j = 0; j < 8; ++j) r += (nts[cc * 8 + j] <= t) ? 1 : 0;
    } else {
#pragma unroll
      for (int j = 0; j < 8; ++j) r += (tsv[j] <= t) ? 1 : 0;
    }
    rowidx[c * 9 + lane] = cc * 9 + r;
  }
}

// ---------------------------------------------------------------------------
// K1s: stats-only GEMM1 pass. A-frags gathered from meanp via rowidx:
// lane(q,l15) of tile t reads meanp[rowidx[t*16+l15]] shorts [q*8,+8) and
// [32+q*8,+8). Accumulate column sum/sumsq of (acc+b1); no pre1 store.
// ---------------------------------------------------------------------------
__global__ __launch_bounds__(256, 3) void k1s_stats(
    const unsigned short* __restrict__ meanp, const int* __restrict__ rowidx,
    const float* __restrict__ W1, const float* __restrict__ b1,
    float* __restrict__ stats)
{
  __shared__ unsigned short W1T[128 * 72];
  __shared__ float redS[256][8];
  __shared__ float redQ[256][8];

  const int tid = threadIdx.x;
  const int lane = tid & 63;
  const int wave = tid >> 6;
  const int l15 = lane & 15;
  const int q = lane >> 4;

  for (int i = tid; i < 8192; i += 256) {
    int n = i >> 6, k = i & 63;
    W1T[n * 72 + k] = (unsigned short)f2bf(W1[k * 128 + n]);
  }
  __syncthreads();

  short8 bf[8][2];
#pragma unroll
  for (int c = 0; c < 8; ++c)
#pragma unroll
    for (int s = 0; s < 2; ++s)
      bf[c][s] = *(const short8*)&W1T[(c * 16 + l15) * 72 + q * 8 + s * 32];

  float b1c[8];
#pragma unroll
  for (int c = 0; c < 8; ++c) b1c[c] = b1[c * 16 + l15];

  float sum8[8], sq8[8];
#pragma unroll
  for (int c = 0; c < 8; ++c) { sum8[c] = 0.f; sq8[c] = 0.f; }

  const int gw = blockIdx.x * 4 + wave;
  const int nw = gridDim.x * 4;

  for (int t = gw; t < kTiles1; t += nw) {
    int rid = rowidx[t * 16 + l15];
    const unsigned short* ap = meanp + (size_t)rid * 64;
    short8 af0 = *(const short8*)(ap + q * 8);
    short8 af1 = *(const short8*)(ap + 32 + q * 8);

    floatx4 acc[8];
#pragma unroll
    for (int c = 0; c < 8; ++c) {
      acc[c] = (floatx4){0.f, 0.f, 0.f, 0.f};
      acc[c] = __builtin_amdgcn_mfma_f32_16x16x32_bf16(af0, bf[c][0], acc[c], 0, 0, 0);
      acc[c] = __builtin_amdgcn_mfma_f32_16x16x32_bf16(af1, bf[c][1], acc[c], 0, 0, 0);
    }
#pragma unroll
    for (int c = 0; c < 8; ++c)
#pragma unroll
      for (int i = 0; i < 4; ++i) {
        float v = acc[c][i] + b1c[c];
        sum8[c] += v; sq8[c] += v * v;
      }
  }

  __syncthreads();
#pragma unroll
  for (int c = 0; c < 8; ++c) { redS[tid][c] = sum8[c]; redQ[tid][c] = sq8[c]; }
  __syncthreads();
  if (tid < 128) {
    int c = tid >> 4, r15 = tid & 15;
    float s = 0.f, qq = 0.f;
#pragma unroll
    for (int w = 0; w < 4; ++w)
#pragma unroll
      for (int p = 0; p < 4; ++p) {
        int T = w * 64 + p * 16 + r15;
        s += redS[T][c]; qq += redQ[T][c];
      }
    atomicAdd(&stats[S_SUM1 + tid], s);
    atomicAdd(&stats[S_SQ1 + tid], qq);
  }
}

// ---------------------------------------------------------------------------
// K2: apply pass, no LDS atomics. One block per 16-node group (144 rows =
// 9 tiles). Phase 1: GEMM1 (A gathered from meanp via rowidx) + BN1+ReLU ->
// H[144][128] bf16 in LDS. Phase 2: wave w owns nodes 4w..4w+3,
// weighted-sum 9 rows/node from LDS, divide, write agg2.
// ---------------------------------------------------------------------------
__global__ __launch_bounds__(256, 2) void k2_apply(
    const unsigned short* __restrict__ meanp, const int* __restrict__ rowidx,
    const float* __restrict__ node_ts, const float* __restrict__ nts,
    const float* __restrict__ W1, const float* __restrict__ b1,
    const float* __restrict__ g1, const float* __restrict__ be1,
    const float* __restrict__ stats, unsigned* __restrict__ agg2dw)
{
  __shared__ unsigned short W1T[128 * 72];   // 18.4 KB
  __shared__ unsigned short H[144 * 128];    // 36.9 KB relu'd layer-1 bf16
  __shared__ float sc[128], sh[128];
  __shared__ float wbuf[144];
  __shared__ float rvs[16];

  const int tid = threadIdx.x;
  const int lane = tid & 63;
  const int wave = tid >> 6;
  const int l15 = lane & 15;
  const int q = lane >> 4;
  const int g = blockIdx.x;          // group id, exact kGroups
  const int n0 = g * 16;

  for (int i = tid; i < 8192; i += 256) {
    int n = i >> 6, k = i & 63;
    W1T[n * 72 + k] = (unsigned short)f2bf(W1[k * 128 + n]);
  }
  if (tid < 128) {
    float mean = stats[S_SUM1 + tid] * (1.f / kM);
    float var  = stats[S_SQ1 + tid] * (1.f / kM) - mean * mean;
    float s    = g1[tid] * rsqrtf(var + kEps);
    sc[tid] = s; sh[tid] = be1[tid] - mean * s;
  }
  if (tid < 144) {
    int nd = n0 + tid / 9, slot = tid % 9;
    wbuf[tid] = (slot < kD) ? ((nts[nd * kD + slot] <= node_ts[nd]) ? 1.f : 0.f)
                            : 1.f;
  }
  __syncthreads();

  short8 bfr[8][2];
#pragma unroll
  for (int c = 0; c < 8; ++c)
#pragma unroll
    for (int s = 0; s < 2; ++s)
      bfr[c][s] = *(const short8*)&W1T[(c * 16 + l15) * 72 + q * 8 + s * 32];

  float scc[8], shc[8];
#pragma unroll
  for (int c = 0; c < 8; ++c) {
    int col = c * 16 + l15;
    scc[c] = sc[col];
    shc[c] = fmaf(b1[col], sc[col], sh[col]);   // fold bias into BN shift
  }
  if (tid < 16) {
    float s = 0.f;
#pragma unroll
    for (int j = 0; j < 9; ++j) s += wbuf[tid * 9 + j];
    rvs[tid] = 1.f / s;
  }

  // ---- phase 1: GEMM1 tiles -> BN1+ReLU -> H (LDS, row-major bf16) ----
  for (int t9 = wave; t9 < 9; t9 += 4) {
    int rid = rowidx[g * 144 + t9 * 16 + l15];
    const unsigned short* ap = meanp + (size_t)rid * 64;
    short8 af0 = *(const short8*)(ap + q * 8);
    short8 af1 = *(const short8*)(ap + 32 + q * 8);

    floatx4 acc[8];
#pragma unroll
    for (int c = 0; c < 8; ++c) {
      acc[c] = (floatx4){0.f, 0.f, 0.f, 0.f};
      acc[c] = __builtin_amdgcn_mfma_f32_16x16x32_bf16(af0, bfr[c][0], acc[c], 0, 0, 0);
      acc[c] = __builtin_amdgcn_mfma_f32_16x16x32_bf16(af1, bfr[c][1], acc[c], 0, 0, 0);
    }
#pragma unroll
    for (int i = 0; i < 4; ++i) {
      int lr = t9 * 16 + q * 4 + i;         // local row in [0,144)
#pragma unroll
      for (int c = 0; c < 8; ++c) {
        int col = c * 16 + l15;
        float h = fmaxf(fmaf(acc[c][i], scc[c], shc[c]), 0.f);
        H[lr * 128 + col] = (unsigned short)f2bf(h);
      }
    }
  }
  __syncthreads();

  // ---- phase 2: per-wave node ownership, register accumulation ----
  const unsigned* Hdw = (const unsigned*)H;
#pragma unroll
  for (int j = 0; j < 4; ++j) {
    int ndl = 4 * wave + j;                 // local node, wave-private
    float s0 = 0.f, s1 = 0.f;
#pragma unroll
    for (int slot = 0; slot < 9; ++slot) {
      int lr = ndl * 9 + slot;
      float w = wbuf[lr];
      unsigned u = Hdw[lr * 64 + lane];
      s0 = fmaf(w, __uint_as_float(u << 16), s0);
      s1 = fmaf(w, __uint_as_float(u & 0xffff0000u), s1);
    }
    float r = rvs[ndl];
    agg2dw[(size_t)(n0 + ndl) * 64 + lane] =
        f2bf(s0 * r) | (f2bf(s1 * r) << 16);
  }
}

// ---------------------------------------------------------------------------
// K3b: MFMA GEMM2: agg2 [N][128] x W2 [128][64] + b2 -> pre2 f32, BN2 stats.
// ---------------------------------------------------------------------------
__global__ __launch_bounds__(256, 3) void k3b_gemm2(
    const unsigned short* __restrict__ agg2, const float* __restrict__ W2,
    const float* __restrict__ b2, float* __restrict__ stats,
    float* __restrict__ pre2)
{
  __shared__ unsigned short W2T[64 * 136];
  __shared__ float redS[256][4];
  __shared__ float redQ[256][4];

  const int tid = threadIdx.x;
  const int lane = tid & 63;
  const int wave = tid >> 6;
  const int l15 = lane & 15;
  const int q = lane >> 4;

  for (int i = tid; i < 8192; i += 256) {
    int n = i >> 7, k = i & 127;
    W2T[n * 136 + k] = (unsigned short)f2bf(W2[k * 64 + n]);
  }
  __syncthreads();

  short8 bfr[4][4];
#pragma unroll
  for (int c = 0; c < 4; ++c)
#pragma unroll
    for (int s = 0; s < 4; ++s)
      bfr[c][s] = *(const short8*)&W2T[(c * 16 + l15) * 136 + q * 8 + s * 32];

  float b2c[4];
#pragma unroll
  for (int c = 0; c < 4; ++c) b2c[c] = b2[c * 16 + l15];

  float sum4[4], sq4[4];
#pragma unroll
  for (int c = 0; c < 4; ++c) { sum4[c] = 0.f; sq4[c] = 0.f; }

  const int gw = blockIdx.x * 4 + wave;
  const int nw = gridDim.x * 4;

  for (int t = gw; t < kTiles3; t += nw) {
    const int r0 = t * 16;
    short8 af[4];
#pragma unroll
    for (int s = 0; s < 4; ++s)
      af[s] = *(const short8*)&agg2[(size_t)(r0 + l15) * 128 + q * 8 + s * 32];

    floatx4 acc[4];
#pragma unroll
    for (int c = 0; c < 4; ++c) {
      acc[c] = (floatx4){0.f, 0.f, 0.f, 0.f};
#pragma unroll
      for (int s = 0; s < 4; ++s)
        acc[c] = __builtin_amdgcn_mfma_f32_16x16x32_bf16(af[s], bfr[c][s], acc[c], 0, 0, 0);
    }
#pragma unroll
    for (int c = 0; c < 4; ++c) {
      int col = c * 16 + l15;
#pragma unroll
      for (int i = 0; i < 4; ++i) {
        float v = acc[c][i] + b2c[c];
        int row = r0 + q * 4 + i;
        pre2[(size_t)row * 64 + col] = v;
        sum4[c] += v; sq4[c] += v * v;
      }
    }
  }

  __syncthreads();
#pragma unroll
  for (int c = 0; c < 4; ++c) { redS[tid][c] = sum4[c]; redQ[tid][c] = sq4[c]; }
  __syncthreads();
  if (tid < 64) {
    int c = tid >> 4, r15 = tid & 15;
    float s = 0.f, qq = 0.f;
#pragma unroll
    for (int w = 0; w < 4; ++w)
#pragma unroll
      for (int p = 0; p < 4; ++p) {
        int T = w * 64 + p * 16 + r15;
        s += redS[T][c]; qq += redQ[T][c];
      }
    atomicAdd(&stats[S_SUM2 + tid], s);
    atomicAdd(&stats[S_SQ2 + tid], qq);
  }
}

// K5: BN2 finalize + embs = relu(BN2(pre2)); embsW = embs * Wd. Zeros out.
__global__ __launch_bounds__(256) void k5_embs(
    const float* __restrict__ pre2, const float* __restrict__ stats,
    const float* __restrict__ g2, const float* __restrict__ be2,
    const float* __restrict__ Wd, float* __restrict__ embs,
    float* __restrict__ embsW, float* __restrict__ out)
{
  __shared__ float sc[64], sh[64], wd[64];
  const int tid = threadIdx.x;
  if (blockIdx.x == 0 && tid == 0) out[0] = 0.f;
  if (tid < 64) {
    float mean = stats[S_SUM2 + tid] * (1.f / kN);
    float var  = stats[S_SQ2 + tid] * (1.f / kN) - mean * mean;
    float s    = g2[tid] * rsqrtf(var + kEps);
    sc[tid] = s; sh[tid] = be2[tid] - mean * s; wd[tid] = Wd[tid];
  }
  __syncthreads();
  int idx = blockIdx.x * 256 + tid;   // grid exact kN*64/256
  int col = idx & 63;
  float e = fmaxf(fmaf(pre2[idx], sc[col], sh[col]), 0.f);
  embs[idx] = e;
  embsW[idx] = e * wd[col];
}

// K6: quarter-wave (16 lanes) per pair. Coalesced 64B row reads, shfl_xor
// butterfly dot, block LDS reduce, one atomic per block.
__global__ __launch_bounds__(256) void k6_loss(
    const float* __restrict__ embs, const float* __restrict__ embsW,
    const int* __restrict__ tgt, const int* __restrict__ neg,
    const float* __restrict__ bd, float* __restrict__ out)
{
  __shared__ float redl[256];
  const int tid = threadIdx.x;
  const int tq = tid & 15;
  const int qb = tid >> 4;
  const float bd0 = bd[0];
  float lsum = 0.f;
  const int e0 = blockIdx.x * 128 + qb * 8;
#pragma unroll
  for (int it = 0; it < 8; ++it) {
    int e = e0 + it;
    if (e < 2 * kE) {
      int i, j; float lab;
      if (e < kE) { i = tgt[e];      j = tgt[kE + e]; lab = 1.f; }
      else        { i = neg[e - kE]; j = neg[e];      lab = 0.f; }
      float4 av = *(const float4*)(embsW + (size_t)i * 64 + tq * 4);
      float4 bv = *(const float4*)(embs  + (size_t)j * 64 + tq * 4);
      float p = av.x * bv.x + av.y * bv.y + av.z * bv.z + av.w * bv.w;
      p += __shfl_xor(p, 1); p += __shfl_xor(p, 2);
      p += __shfl_xor(p, 4); p += __shfl_xor(p, 8);
      p += bd0;
      float l = fmaxf(p, 0.f) - p * lab + log1pf(expf(-fabsf(p)));
      if (tq == 0) lsum += l;
    }
  }
  redl[tid] = lsum;
  __syncthreads();
  for (int s = 128; s > 0; s >>= 1) {
    if (tid < s) redl[tid] += redl[tid + s];
    __syncthreads();
  }
  if (tid == 0) atomicAdd(out, redl[0] * (1.f / (2 * kE)));
}

extern "C" void kernel_launch(void* const* d_in, const int* in_sizes, int n_in,
                              void* d_out, int out_size, void* d_ws, size_t ws_size,
                              hipStream_t stream) {
  (void)in_sizes; (void)n_in; (void)out_size; (void)ws_size;
  const float* x       = (const float*)d_in[0];
  const float* node_ts = (const float*)d_in[1];
  const int*   nidx    = (const int*)d_in[2];
  const float* nts     = (const float*)d_in[3];
  const int*   tgt     = (const int*)d_in[4];
  const int*   neg     = (const int*)d_in[5];
  const float* W1      = (const float*)d_in[6];
  const float* b1      = (const float*)d_in[7];
  const float* g1      = (const float*)d_in[8];
  const float* be1     = (const float*)d_in[9];
  const float* W2      = (const float*)d_in[10];
  const float* b2      = (const float*)d_in[11];
  const float* g2      = (const float*)d_in[12];
  const float* be2     = (const float*)d_in[13];
  const float* Wd      = (const float*)d_in[14];
  const float* bd      = (const float*)d_in[15];

  char* ws = (char*)d_ws;
  unsigned short* meanp = (unsigned short*)ws;               // [kN][9][64]
  unsigned short* agg2  = (unsigned short*)(ws + OFF_AGG2);
  float* pre2   = (float*)(ws + OFF_PRE2);
  float* embs   = (float*)(ws + OFF_EMBS);
  float* embsW  = (float*)(ws + OFF_EMBSW);
  float* stats  = (float*)(ws + OFF_STATS);
  int*   rowidx = (int*)(ws + OFF_ROWIDX);
  float* out    = (float*)d_out;

  kA_prep<<<kN / 4, 256, 0, stream>>>(x, node_ts, nidx, nts, meanp, rowidx, stats);
  k1s_stats<<<512, 256, 0, stream>>>(meanp, rowidx, W1, b1, stats);
  k2_apply<<<kGroups, 256, 0, stream>>>(meanp, rowidx, node_ts, nts, W1, b1,
                                        g1, be1, stats, (unsigned*)agg2);
  k3b_gemm2<<<160, 256, 0, stream>>>(agg2, W2, b2, stats, pre2);
  k5_embs<<<kN * 64 / 256, 256, 0, stream>>>(pre2, stats, g2, be2, Wd, embs,
                                             embsW, out);
  k6_loss<<<(2 * kE + 127) / 128, 256, 0, stream>>>(embs, embsW, tgt, neg, bd, out);
}